// Round 3
// baseline (462.399 us; speedup 1.0000x reference)
//
#include <hip/hip_runtime.h>

#define HID 896
#define NH 14
#define NKV 2
#define NREP 7
#define SEQ 2048
#define BT 2
#define NTOK (BT*SEQ)
#define CSCALE 0.18033688011112042f   // (1/8) * log2(e)

typedef __attribute__((ext_vector_type(8))) short bf16x8;
typedef __attribute__((ext_vector_type(8))) unsigned short u16x8;
typedef __attribute__((ext_vector_type(4))) float fx4;
typedef __attribute__((ext_vector_type(4))) short s16x4;
typedef _Float16 f16x4 __attribute__((ext_vector_type(4)));

__device__ __forceinline__ unsigned short f2b(float x){
  union { float f; unsigned u; } a; a.f = x;
  unsigned r = a.u + 0x7FFFu + ((a.u >> 16) & 1u);   // RNE
  return (unsigned short)(r >> 16);
}
__device__ __forceinline__ unsigned short f2h(float x){
  union { _Float16 h; unsigned short u; } a; a.h = (_Float16)x; return a.u;
}

// ---------------- fused QKV projection + bias + RoPE ----------------
// grid (NTOK/64, 18), block 256. bn 0..13 -> Q head; 14,15 -> K; 16,17 -> V (f16, transposed)
__global__ __launch_bounds__(256) void qkv_rope_kernel(
    const float* __restrict__ hidden, const int* __restrict__ pos,
    const float* __restrict__ Wq, const float* __restrict__ bq,
    const float* __restrict__ Wk, const float* __restrict__ bk,
    const float* __restrict__ Wv, const float* __restrict__ bv,
    unsigned short* __restrict__ qo, unsigned short* __restrict__ ko,
    unsigned short* __restrict__ vt)
{
  __shared__ short As[64*40];
  __shared__ short Bs[64*40];
  const int tid = threadIdx.x;
  const int bm = blockIdx.x, bn = blockIdx.y;
  const int w = tid >> 6, l = tid & 63, l15 = l & 15, l16 = l >> 4;

  const float *W, *bias; int kind, hloc;
  if (bn < NH)      { W = Wq + (size_t)bn*64*HID;      bias = bq + bn*64;      kind = 0; hloc = bn; }
  else if (bn < 16) { W = Wk + (size_t)(bn-NH)*64*HID; bias = bk + (bn-NH)*64; kind = 1; hloc = bn-NH; }
  else              { W = Wv + (size_t)(bn-16)*64*HID; bias = bv + (bn-16)*64; kind = 2; hloc = bn-16; }

  fx4 acc[4] = {{0,0,0,0},{0,0,0,0},{0,0,0,0},{0,0,0,0}};

  const int r = tid >> 2, c8 = (tid & 3) * 8;
  const float* ap0 = hidden + (size_t)(bm*64 + r)*HID + c8;
  const float* bp0 = W + (size_t)r*HID + c8;

  for (int kc = 0; kc < HID; kc += 32){
    __syncthreads();
    float4 a0 = *(const float4*)(ap0 + kc);
    float4 a1 = *(const float4*)(ap0 + kc + 4);
    float4 b0 = *(const float4*)(bp0 + kc);
    float4 b1 = *(const float4*)(bp0 + kc + 4);
    bf16x8 avv, bvv;
    avv[0]=(short)f2b(a0.x); avv[1]=(short)f2b(a0.y); avv[2]=(short)f2b(a0.z); avv[3]=(short)f2b(a0.w);
    avv[4]=(short)f2b(a1.x); avv[5]=(short)f2b(a1.y); avv[6]=(short)f2b(a1.z); avv[7]=(short)f2b(a1.w);
    bvv[0]=(short)f2b(b0.x); bvv[1]=(short)f2b(b0.y); bvv[2]=(short)f2b(b0.z); bvv[3]=(short)f2b(b0.w);
    bvv[4]=(short)f2b(b1.x); bvv[5]=(short)f2b(b1.y); bvv[6]=(short)f2b(b1.z); bvv[7]=(short)f2b(b1.w);
    *(bf16x8*)&As[r*40 + c8] = avv;
    *(bf16x8*)&Bs[r*40 + c8] = bvv;
    __syncthreads();
    bf16x8 af = *(bf16x8*)&As[(w*16 + l15)*40 + l16*8];
#pragma unroll
    for (int nt = 0; nt < 4; nt++){
      bf16x8 bfr = *(bf16x8*)&Bs[(nt*16 + l15)*40 + l16*8];
      acc[nt] = __builtin_amdgcn_mfma_f32_16x16x32_bf16(af, bfr, acc[nt], 0, 0, 0);
    }
  }

  float bl[4];
#pragma unroll
  for (int nt = 0; nt < 4; nt++) bl[nt] = bias[nt*16 + l15];

  if (kind == 2){
    // V stored TRANSPOSED as f16: (B, NKV, D=64, SEQ)
#pragma unroll
    for (int j = 0; j < 4; j++){
      int grow = bm*64 + w*16 + l16*4 + j;
      int b = grow >> 11, s = grow & (SEQ-1);
      unsigned short* dst = vt + ((size_t)(b*NKV + hloc)*64)*SEQ + s;
#pragma unroll
      for (int nt = 0; nt < 4; nt++)
        dst[(size_t)(nt*16 + l15)*SEQ] = f2h(acc[nt][j] + bl[nt]);
    }
  } else {
    float invf[2];
#pragma unroll
    for (int nt = 0; nt < 2; nt++)
      invf[nt] = exp2f(-(float)(nt*16 + l15) * 0.62286151779138041f);
#pragma unroll
    for (int j = 0; j < 4; j++){
      int grow = bm*64 + w*16 + l16*4 + j;
      int b = grow >> 11, s = grow & (SEQ-1);
      float p = (float)pos[grow];
      unsigned short* dst = (kind == 0)
          ? qo + ((size_t)(b*NH  + hloc)*SEQ + s)*64
          : ko + ((size_t)(b*NKV + hloc)*SEQ + s)*64;
#pragma unroll
      for (int nt = 0; nt < 2; nt++){
        int d = nt*16 + l15;
        float f = p * invf[nt];
        float sv, cv;
        sincosf(f, &sv, &cv);
        float x1 = acc[nt][j]   + bl[nt];
        float x2 = acc[nt+2][j] + bl[nt+2];
        dst[d]    = f2b(x1*cv - x2*sv);
        dst[d+32] = f2b(x2*cv + x1*sv);
      }
    }
  }
}

// ---------------- flash attention v3: S^T/O^T orientation, zero LDS ----------------
// grid (SEQ/64, NH, BT) with t = 31-bx (LPT), block 256 (4 independent waves).
// S^T = K·Q^T via 16x16x32 bf16 MFMA: C-layout puts qrow on lanes, keys on regs ->
// in-register softmax (2 shuffles), P feeds PV directly as 16x16x16 f16 B-frags.
__global__ __launch_bounds__(256) void attn_kernel(
    const unsigned short* __restrict__ q, const unsigned short* __restrict__ k,
    const unsigned short* __restrict__ vt, unsigned short* __restrict__ ao)
{
  const int tid = threadIdx.x;
  const int w = tid >> 6, l = tid & 63, l15 = l & 15, q4 = l >> 4;
  const int t = (int)gridDim.x - 1 - (int)blockIdx.x;
  const int h = blockIdx.y, b = blockIdx.z, kvh = h / NREP;
  const int bq0 = t*64;
  const int qrow_g = bq0 + w*16 + l15;

  const unsigned short* qp = q + ((size_t)(b*NH + h)*SEQ + qrow_g)*64;
  bf16x8 qf0 = *(const bf16x8*)(qp + q4*8);        // Q B-frag, d 0..31
  bf16x8 qf1 = *(const bf16x8*)(qp + 32 + q4*8);   // d 32..63

  fx4 o[4] = {{0,0,0,0},{0,0,0,0},{0,0,0,0},{0,0,0,0}};  // O^T: d=nt*16+q4*4+reg, qrow=l15
  float m_run = -1e30f, l_run = 0.f;

  const unsigned short* kbase = k + ((size_t)(b*NKV + kvh)*SEQ)*64;
  const _Float16* vtb = (const _Float16*)vt + ((size_t)(b*NKV + kvh)*64)*SEQ;

  // preload K frags for tile 0 (A-frag: m=key, k=d)
  bf16x8 kf0[4], kf1[4];
#pragma unroll
  for (int tl = 0; tl < 4; tl++){
    const unsigned short* kp = kbase + (size_t)(tl*16 + l15)*64;
    kf0[tl] = *(const bf16x8*)(kp + q4*8);
    kf1[tl] = *(const bf16x8*)(kp + 32 + q4*8);
  }

  for (int kt = 0; kt <= t; kt++){
    const int key0 = kt*64;

    // S^T = K·Q^T : D[m=key][n=qrow]; per lane: qrow=l15, key=key0+tl*16+q4*4+j
    fx4 s[4] = {{0,0,0,0},{0,0,0,0},{0,0,0,0},{0,0,0,0}};
#pragma unroll
    for (int tl = 0; tl < 4; tl++){
      s[tl] = __builtin_amdgcn_mfma_f32_16x16x32_bf16(kf0[tl], qf0, s[tl], 0,0,0);
      s[tl] = __builtin_amdgcn_mfma_f32_16x16x32_bf16(kf1[tl], qf1, s[tl], 0,0,0);
    }

    // prefetch V^T A-frags for this tile (f16, 8B each) — latency hidden under softmax
    f16x4 vf[4][4];
#pragma unroll
    for (int nt = 0; nt < 4; nt++)
#pragma unroll
      for (int tl = 0; tl < 4; tl++)
        vf[nt][tl] = *(const f16x4*)(vtb + (size_t)(nt*16 + l15)*SEQ + key0 + tl*16 + q4*4);

    // prefetch next K tile (address clamped so last iter stays in-bounds; values unused)
    const int nk0 = (kt < t) ? key0 + 64 : 0;
    bf16x8 kn0[4], kn1[4];
#pragma unroll
    for (int tl = 0; tl < 4; tl++){
      const unsigned short* kp = kbase + (size_t)(nk0 + tl*16 + l15)*64;
      kn0[tl] = *(const bf16x8*)(kp + q4*8);
      kn1[tl] = *(const bf16x8*)(kp + 32 + q4*8);
    }

    // in-register online softmax over 16 key-values per lane (+2 shuffles per tree)
    float tv[16];
#pragma unroll
    for (int tl = 0; tl < 4; tl++)
#pragma unroll
      for (int j = 0; j < 4; j++) tv[tl*4+j] = s[tl][j]*CSCALE;
    if (kt == t){
#pragma unroll
      for (int tl = 0; tl < 4; tl++)
#pragma unroll
        for (int j = 0; j < 4; j++)
          if (key0 + tl*16 + q4*4 + j > qrow_g) tv[tl*4+j] = -1e30f;
    }
    float mx = tv[0];
#pragma unroll
    for (int i = 1; i < 16; i++) mx = fmaxf(mx, tv[i]);
    mx = fmaxf(mx, __shfl_xor(mx, 16));
    mx = fmaxf(mx, __shfl_xor(mx, 32));
    float mn = fmaxf(m_run, mx);
    float al = exp2f(m_run - mn);
    m_run = mn;
    float p[16], rs = 0.f;
#pragma unroll
    for (int i = 0; i < 16; i++){ p[i] = exp2f(tv[i] - mn); rs += p[i]; }
    rs += __shfl_xor(rs, 16);
    rs += __shfl_xor(rs, 32);
    l_run = l_run*al + rs;
#pragma unroll
    for (int nt = 0; nt < 4; nt++)
#pragma unroll
      for (int j = 0; j < 4; j++) o[nt][j] *= al;

    // P^T B-frags directly from registers (k=key=q4*4+j, n=qrow=l15)
    f16x4 pf[4];
#pragma unroll
    for (int tl = 0; tl < 4; tl++){
      pf[tl][0] = (_Float16)p[tl*4+0];
      pf[tl][1] = (_Float16)p[tl*4+1];
      pf[tl][2] = (_Float16)p[tl*4+2];
      pf[tl][3] = (_Float16)p[tl*4+3];
    }

    // O^T += V^T · P^T  (16x16x16 f16 MFMA)
#pragma unroll
    for (int nt = 0; nt < 4; nt++)
#pragma unroll
      for (int tl = 0; tl < 4; tl++)
        o[nt] = __builtin_amdgcn_mfma_f32_16x16x16f16(vf[nt][tl], pf[tl], o[nt], 0,0,0);

#pragma unroll
    for (int tl = 0; tl < 4; tl++){ kf0[tl] = kn0[tl]; kf1[tl] = kn1[tl]; }
  }

  // epilogue: O^T lane l15=qrow holds d = nt*16 + q4*4 + {0..3} -> 8B packed stores
  float inv = 1.0f / l_run;
  unsigned short* dst = ao + ((size_t)(b*SEQ + qrow_g))*HID + h*64;
#pragma unroll
  for (int nt = 0; nt < 4; nt++){
    s16x4 ov;
    ov[0] = (short)f2b(o[nt][0]*inv);
    ov[1] = (short)f2b(o[nt][1]*inv);
    ov[2] = (short)f2b(o[nt][2]*inv);
    ov[3] = (short)f2b(o[nt][3]*inv);
    *(s16x4*)(dst + nt*16 + q4*4) = ov;
  }
}

// ---------------- output projection: attn(bf16) @ Wo^T -> fp32 ----------------
// grid (NTOK/64, 14), block 256
__global__ __launch_bounds__(256) void out_gemm_kernel(
    const unsigned short* __restrict__ A, const float* __restrict__ Wo,
    float* __restrict__ out)
{
  __shared__ short As[64*40];
  __shared__ short Bs[64*40];
  const int tid = threadIdx.x;
  const int bm = blockIdx.x, bn = blockIdx.y;
  const int w = tid >> 6, l = tid & 63, l15 = l & 15, l16 = l >> 4;

  fx4 acc[4] = {{0,0,0,0},{0,0,0,0},{0,0,0,0},{0,0,0,0}};
  const int r = tid >> 2, c8 = (tid & 3)*8;
  const unsigned short* ap0 = A + (size_t)(bm*64 + r)*HID + c8;
  const float* bp0 = Wo + (size_t)(bn*64 + r)*HID + c8;

  for (int kc = 0; kc < HID; kc += 32){
    __syncthreads();
    u16x8 a8 = *(const u16x8*)(ap0 + kc);
    float4 b0 = *(const float4*)(bp0 + kc);
    float4 b1 = *(const float4*)(bp0 + kc + 4);
    bf16x8 bvv;
    bvv[0]=(short)f2b(b0.x); bvv[1]=(short)f2b(b0.y); bvv[2]=(short)f2b(b0.z); bvv[3]=(short)f2b(b0.w);
    bvv[4]=(short)f2b(b1.x); bvv[5]=(short)f2b(b1.y); bvv[6]=(short)f2b(b1.z); bvv[7]=(short)f2b(b1.w);
    *(u16x8*)&As[r*40 + c8] = a8;
    *(bf16x8*)&Bs[r*40 + c8] = bvv;
    __syncthreads();
    bf16x8 af = *(bf16x8*)&As[(w*16 + l15)*40 + l16*8];
#pragma unroll
    for (int nt = 0; nt < 4; nt++){
      bf16x8 bfr = *(bf16x8*)&Bs[(nt*16 + l15)*40 + l16*8];
      acc[nt] = __builtin_amdgcn_mfma_f32_16x16x32_bf16(af, bfr, acc[nt], 0, 0, 0);
    }
  }

#pragma unroll
  for (int j = 0; j < 4; j++){
    int grow = bm*64 + w*16 + l16*4 + j;
    float* dst = out + (size_t)grow*HID + bn*64;
#pragma unroll
    for (int nt = 0; nt < 4; nt++)
      dst[nt*16 + l15] = acc[nt][j];
  }
}

extern "C" void kernel_launch(void* const* d_in, const int* in_sizes, int n_in,
                              void* d_out, int out_size, void* d_ws, size_t ws_size,
                              hipStream_t stream)
{
  const float* hidden = (const float*)d_in[0];
  const int*   pos    = (const int*)d_in[1];
  const float* Wq = (const float*)d_in[2]; const float* bq = (const float*)d_in[3];
  const float* Wk = (const float*)d_in[4]; const float* bk = (const float*)d_in[5];
  const float* Wv = (const float*)d_in[6]; const float* bv = (const float*)d_in[7];
  const float* Wo = (const float*)d_in[8];

  unsigned short* qws  = (unsigned short*)d_ws;                      // (B,NH,S,64) bf16
  unsigned short* kws  = qws + (size_t)BT*NH*SEQ*64;                 // (B,NKV,S,64) bf16
  unsigned short* vtws = kws + (size_t)BT*NKV*SEQ*64;                // (B,NKV,64,S) f16 V^T
  unsigned short* aws  = vtws + (size_t)BT*NKV*SEQ*64;               // (B,S,896) bf16

  qkv_rope_kernel<<<dim3(NTOK/64, 18), 256, 0, stream>>>(
      hidden, pos, Wq, bq, Wk, bk, Wv, bv, qws, kws, vtws);
  attn_kernel<<<dim3(SEQ/64, NH, BT), 256, 0, stream>>>(qws, kws, vtws, aws);
  out_gemm_kernel<<<dim3(NTOK/64, NH), 256, 0, stream>>>(aws, Wo, (float*)d_out);
}

// Round 4
// 186.563 us; speedup vs baseline: 2.4785x; 2.4785x over previous
//
#include <hip/hip_runtime.h>

#define HID 896
#define NH 14
#define NKV 2
#define NREP 7
#define SEQ 2048
#define BT 2
#define NTOK (BT*SEQ)
#define CSCALE 0.18033688011112042f   // (1/8) * log2(e)

typedef __attribute__((ext_vector_type(8))) short bf16x8;
typedef __attribute__((ext_vector_type(8))) unsigned short u16x8;
typedef __attribute__((ext_vector_type(4))) float fx4;
typedef __attribute__((ext_vector_type(4))) short s16x4;
typedef _Float16 f16x4 __attribute__((ext_vector_type(4)));

__device__ __forceinline__ unsigned short f2b(float x){
  union { float f; unsigned u; } a; a.f = x;
  unsigned r = a.u + 0x7FFFu + ((a.u >> 16) & 1u);   // RNE
  return (unsigned short)(r >> 16);
}
__device__ __forceinline__ unsigned short f2h(float x){
  union { _Float16 h; unsigned short u; } a; a.h = (_Float16)x; return a.u;
}

// ---------------- fused QKV projection + bias + RoPE ----------------
// grid (NTOK/64, 18), block 256. bn 0..13 -> Q head; 14,15 -> K; 16,17 -> V
// V written as f16 in BLOCK-TRANSPOSED tiles: (B, NKV, S/64, 64d, 64key) contiguous 8KB tiles
__global__ __launch_bounds__(256) void qkv_rope_kernel(
    const float* __restrict__ hidden, const int* __restrict__ pos,
    const float* __restrict__ Wq, const float* __restrict__ bq,
    const float* __restrict__ Wk, const float* __restrict__ bk,
    const float* __restrict__ Wv, const float* __restrict__ bv,
    unsigned short* __restrict__ qo, unsigned short* __restrict__ ko,
    unsigned short* __restrict__ vt)
{
  __shared__ short As[64*40];
  __shared__ short Bs[64*40];
  const int tid = threadIdx.x;
  const int bm = blockIdx.x, bn = blockIdx.y;
  const int w = tid >> 6, l = tid & 63, l15 = l & 15, l16 = l >> 4;

  const float *W, *bias; int kind, hloc;
  if (bn < NH)      { W = Wq + (size_t)bn*64*HID;      bias = bq + bn*64;      kind = 0; hloc = bn; }
  else if (bn < 16) { W = Wk + (size_t)(bn-NH)*64*HID; bias = bk + (bn-NH)*64; kind = 1; hloc = bn-NH; }
  else              { W = Wv + (size_t)(bn-16)*64*HID; bias = bv + (bn-16)*64; kind = 2; hloc = bn-16; }

  fx4 acc[4] = {{0,0,0,0},{0,0,0,0},{0,0,0,0},{0,0,0,0}};

  const int r = tid >> 2, c8 = (tid & 3) * 8;
  const float* ap0 = hidden + (size_t)(bm*64 + r)*HID + c8;
  const float* bp0 = W + (size_t)r*HID + c8;

  for (int kc = 0; kc < HID; kc += 32){
    __syncthreads();
    float4 a0 = *(const float4*)(ap0 + kc);
    float4 a1 = *(const float4*)(ap0 + kc + 4);
    float4 b0 = *(const float4*)(bp0 + kc);
    float4 b1 = *(const float4*)(bp0 + kc + 4);
    bf16x8 avv, bvv;
    avv[0]=(short)f2b(a0.x); avv[1]=(short)f2b(a0.y); avv[2]=(short)f2b(a0.z); avv[3]=(short)f2b(a0.w);
    avv[4]=(short)f2b(a1.x); avv[5]=(short)f2b(a1.y); avv[6]=(short)f2b(a1.z); avv[7]=(short)f2b(a1.w);
    bvv[0]=(short)f2b(b0.x); bvv[1]=(short)f2b(b0.y); bvv[2]=(short)f2b(b0.z); bvv[3]=(short)f2b(b0.w);
    bvv[4]=(short)f2b(b1.x); bvv[5]=(short)f2b(b1.y); bvv[6]=(short)f2b(b1.z); bvv[7]=(short)f2b(b1.w);
    *(bf16x8*)&As[r*40 + c8] = avv;
    *(bf16x8*)&Bs[r*40 + c8] = bvv;
    __syncthreads();
    bf16x8 af = *(bf16x8*)&As[(w*16 + l15)*40 + l16*8];
#pragma unroll
    for (int nt = 0; nt < 4; nt++){
      bf16x8 bfr = *(bf16x8*)&Bs[(nt*16 + l15)*40 + l16*8];
      acc[nt] = __builtin_amdgcn_mfma_f32_16x16x32_bf16(af, bfr, acc[nt], 0, 0, 0);
    }
  }

  float bl[4];
#pragma unroll
  for (int nt = 0; nt < 4; nt++) bl[nt] = bias[nt*16 + l15];

  if (kind == 2){
#pragma unroll
    for (int j = 0; j < 4; j++){
      int grow = bm*64 + w*16 + l16*4 + j;
      int b = grow >> 11, s = grow & (SEQ-1);
      int tile = s >> 6, key = s & 63;
      unsigned short* dst = vt + (size_t)(((b*NKV + hloc)*(SEQ/64) + tile)*4096);
#pragma unroll
      for (int nt = 0; nt < 4; nt++)
        dst[(nt*16 + l15)*64 + key] = f2h(acc[nt][j] + bl[nt]);
    }
  } else {
    float invf[2];
#pragma unroll
    for (int nt = 0; nt < 2; nt++)
      invf[nt] = exp2f(-(float)(nt*16 + l15) * 0.62286151779138041f);
#pragma unroll
    for (int j = 0; j < 4; j++){
      int grow = bm*64 + w*16 + l16*4 + j;
      int b = grow >> 11, s = grow & (SEQ-1);
      float p = (float)pos[grow];
      unsigned short* dst = (kind == 0)
          ? qo + ((size_t)(b*NH  + hloc)*SEQ + s)*64
          : ko + ((size_t)(b*NKV + hloc)*SEQ + s)*64;
#pragma unroll
      for (int nt = 0; nt < 2; nt++){
        int d = nt*16 + l15;
        float f = p * invf[nt];
        float sv, cv;
        sincosf(f, &sv, &cv);
        float x1 = acc[nt][j]   + bl[nt];
        float x2 = acc[nt+2][j] + bl[nt+2];
        dst[d]    = f2b(x1*cv - x2*sv);
        dst[d+32] = f2b(x2*cv + x1*sv);
      }
    }
  }
}

// -------- per-tile softmax + PV update (S^T orientation; math verified in R3) --------
__device__ __forceinline__ void smax_pv(
    const fx4* s, bool diag, int wl /*row-in-tile*/, int q4,
    float& m_run, float& l_run, fx4* o, const f16x4 vf[4][4])
{
  float tv[16];
#pragma unroll
  for (int tl = 0; tl < 4; tl++)
#pragma unroll
    for (int j = 0; j < 4; j++){
      float x = s[tl][j]*CSCALE;
      if (diag && (tl*16 + q4*4 + j > wl)) x = -1e30f;
      tv[tl*4+j] = x;
    }
  float mx = tv[0];
#pragma unroll
  for (int i = 1; i < 16; i++) mx = fmaxf(mx, tv[i]);
  mx = fmaxf(mx, __shfl_xor(mx, 16));
  mx = fmaxf(mx, __shfl_xor(mx, 32));
  float mn = fmaxf(m_run, mx);
  float al = exp2f(m_run - mn);
  m_run = mn;
  float p[16], rs = 0.f;
#pragma unroll
  for (int i = 0; i < 16; i++){ p[i] = exp2f(tv[i] - mn); rs += p[i]; }
  rs += __shfl_xor(rs, 16);
  rs += __shfl_xor(rs, 32);
  l_run = l_run*al + rs;
#pragma unroll
  for (int nt = 0; nt < 4; nt++)
#pragma unroll
    for (int j = 0; j < 4; j++) o[nt][j] *= al;
  f16x4 pf[4];
#pragma unroll
  for (int tl = 0; tl < 4; tl++){
    pf[tl][0] = (_Float16)p[tl*4+0];
    pf[tl][1] = (_Float16)p[tl*4+1];
    pf[tl][2] = (_Float16)p[tl*4+2];
    pf[tl][3] = (_Float16)p[tl*4+3];
  }
#pragma unroll
  for (int nt = 0; nt < 4; nt++)
#pragma unroll
    for (int tl = 0; tl < 4; tl++)
      o[nt] = __builtin_amdgcn_mfma_f32_16x16x16f16(vf[nt][tl], pf[tl], o[nt], 0,0,0);
}

// ---------------- flash attention v4: coalesced LDS staging + causal pairing ----------------
// grid (16, NH, BT), block 256. Block handles q-tiles tlo=bx and thi=31-bx (64 rows each),
// sharing K/V tiles + K fragments -> every block does exactly 33 tile-updates (no tail).
__global__ __launch_bounds__(256) void attn_kernel(
    const unsigned short* __restrict__ q, const unsigned short* __restrict__ k,
    const unsigned short* __restrict__ vt, unsigned short* __restrict__ ao)
{
  __shared__ short Ks[64*72];   // K tile: row=key, 64 d, stride 72 (conflict-floor)
  __shared__ short Vt[64*72];   // V^T tile: row=d, 64 keys, stride 72

  const int tid = threadIdx.x;
  const int w = tid >> 6, l = tid & 63, l15 = l & 15, q4 = l >> 4;
  const int tlo = blockIdx.x, thi = 31 - tlo;
  const int h = blockIdx.y, b = blockIdx.z, kvh = h / NREP;
  const int wl = w*16 + l15;   // row within a 64-row q-tile

  // Q fragments for both tiles (one-time gather, amortized over 33 iters)
  const unsigned short* qbase = q + ((size_t)(b*NH + h)*SEQ)*64;
  const unsigned short* qpA = qbase + (size_t)(thi*64 + wl)*64;
  const unsigned short* qpB = qbase + (size_t)(tlo*64 + wl)*64;
  bf16x8 qA0 = *(const bf16x8*)(qpA + q4*8), qA1 = *(const bf16x8*)(qpA + 32 + q4*8);
  bf16x8 qB0 = *(const bf16x8*)(qpB + q4*8), qB1 = *(const bf16x8*)(qpB + 32 + q4*8);

  fx4 oA[4] = {{0,0,0,0},{0,0,0,0},{0,0,0,0},{0,0,0,0}};
  fx4 oB[4] = {{0,0,0,0},{0,0,0,0},{0,0,0,0},{0,0,0,0}};
  float mA = -1e30f, lA = 0.f, mB = -1e30f, lB = 0.f;

  const unsigned short* kbase = k  + ((size_t)(b*NKV + kvh)*SEQ)*64;           // natural: tiles contiguous
  const unsigned short* vbase = vt + (size_t)((b*NKV + kvh)*(SEQ/64))*4096;    // V^T tiles contiguous

  // prefetch tile 0 into registers (coalesced: 256 threads x 16B x 2 passes = 8KB)
  u16x8 kreg[2], vreg[2];
#pragma unroll
  for (int p = 0; p < 2; p++){
    int n = p*256 + tid;
    kreg[p] = *(const u16x8*)(kbase + n*8);
    vreg[p] = *(const u16x8*)(vbase + n*8);
  }

  for (int kt = 0; kt <= thi; kt++){
    // stage registers -> padded LDS (write groups (r+g)%8 uniform -> conflict floor)
#pragma unroll
    for (int p = 0; p < 2; p++){
      int n = p*256 + tid, rr = n >> 3, g = n & 7;
      *(u16x8*)&Ks[rr*72 + g*8] = kreg[p];
      *(u16x8*)&Vt[rr*72 + g*8] = vreg[p];
    }
    __syncthreads();

    // prefetch next tile while computing this one
    if (kt < thi){
      const unsigned short* kn = kbase + (size_t)(kt+1)*4096;
      const unsigned short* vn = vbase + (size_t)(kt+1)*4096;
#pragma unroll
      for (int p = 0; p < 2; p++){
        int n = p*256 + tid;
        kreg[p] = *(const u16x8*)(kn + n*8);
        vreg[p] = *(const u16x8*)(vn + n*8);
      }
    }

    // fragments from LDS (K frags shared by both q-tiles)
    bf16x8 kf0[4], kf1[4];
#pragma unroll
    for (int tl = 0; tl < 4; tl++){
      kf0[tl] = *(bf16x8*)&Ks[(tl*16 + l15)*72 + q4*8];
      kf1[tl] = *(bf16x8*)&Ks[(tl*16 + l15)*72 + 32 + q4*8];
    }
    f16x4 vf[4][4];
#pragma unroll
    for (int nt = 0; nt < 4; nt++)
#pragma unroll
      for (int tl = 0; tl < 4; tl++)
        vf[nt][tl] = *(f16x4*)&Vt[(nt*16 + l15)*72 + tl*16 + q4*4];

    // tile thi (active for all kt)
    {
      fx4 s[4] = {{0,0,0,0},{0,0,0,0},{0,0,0,0},{0,0,0,0}};
#pragma unroll
      for (int tl = 0; tl < 4; tl++){
        s[tl] = __builtin_amdgcn_mfma_f32_16x16x32_bf16(kf0[tl], qA0, s[tl], 0,0,0);
        s[tl] = __builtin_amdgcn_mfma_f32_16x16x32_bf16(kf1[tl], qA1, s[tl], 0,0,0);
      }
      smax_pv(s, kt == thi, wl, q4, mA, lA, oA, vf);
    }
    // tile tlo (active while kt <= tlo) — uniform branch
    if (kt <= tlo){
      fx4 s[4] = {{0,0,0,0},{0,0,0,0},{0,0,0,0},{0,0,0,0}};
#pragma unroll
      for (int tl = 0; tl < 4; tl++){
        s[tl] = __builtin_amdgcn_mfma_f32_16x16x32_bf16(kf0[tl], qB0, s[tl], 0,0,0);
        s[tl] = __builtin_amdgcn_mfma_f32_16x16x32_bf16(kf1[tl], qB1, s[tl], 0,0,0);
      }
      smax_pv(s, kt == tlo, wl, q4, mB, lB, oB, vf);
    }
    __syncthreads();   // protect LDS before next stage
  }

  // epilogue (O^T: lane l15 = qrow, d = nt*16 + q4*4 + j) — 8B packed stores
  {
    float inv = 1.0f / lA;
    unsigned short* dst = ao + ((size_t)(b*SEQ + thi*64 + wl))*HID + h*64;
#pragma unroll
    for (int nt = 0; nt < 4; nt++){
      s16x4 ov;
      ov[0] = (short)f2b(oA[nt][0]*inv); ov[1] = (short)f2b(oA[nt][1]*inv);
      ov[2] = (short)f2b(oA[nt][2]*inv); ov[3] = (short)f2b(oA[nt][3]*inv);
      *(s16x4*)(dst + nt*16 + q4*4) = ov;
    }
  }
  {
    float inv = 1.0f / lB;
    unsigned short* dst = ao + ((size_t)(b*SEQ + tlo*64 + wl))*HID + h*64;
#pragma unroll
    for (int nt = 0; nt < 4; nt++){
      s16x4 ov;
      ov[0] = (short)f2b(oB[nt][0]*inv); ov[1] = (short)f2b(oB[nt][1]*inv);
      ov[2] = (short)f2b(oB[nt][2]*inv); ov[3] = (short)f2b(oB[nt][3]*inv);
      *(s16x4*)(dst + nt*16 + q4*4) = ov;
    }
  }
}

// ---------------- output projection: attn(bf16) @ Wo^T -> fp32 ----------------
// grid (NTOK/64, 14), block 256
__global__ __launch_bounds__(256) void out_gemm_kernel(
    const unsigned short* __restrict__ A, const float* __restrict__ Wo,
    float* __restrict__ out)
{
  __shared__ short As[64*40];
  __shared__ short Bs[64*40];
  const int tid = threadIdx.x;
  const int bm = blockIdx.x, bn = blockIdx.y;
  const int w = tid >> 6, l = tid & 63, l15 = l & 15, l16 = l >> 4;

  fx4 acc[4] = {{0,0,0,0},{0,0,0,0},{0,0,0,0},{0,0,0,0}};
  const int r = tid >> 2, c8 = (tid & 3)*8;
  const unsigned short* ap0 = A + (size_t)(bm*64 + r)*HID + c8;
  const float* bp0 = Wo + (size_t)(bn*64 + r)*HID + c8;

  for (int kc = 0; kc < HID; kc += 32){
    __syncthreads();
    u16x8 a8 = *(const u16x8*)(ap0 + kc);
    float4 b0 = *(const float4*)(bp0 + kc);
    float4 b1 = *(const float4*)(bp0 + kc + 4);
    bf16x8 bvv;
    bvv[0]=(short)f2b(b0.x); bvv[1]=(short)f2b(b0.y); bvv[2]=(short)f2b(b0.z); bvv[3]=(short)f2b(b0.w);
    bvv[4]=(short)f2b(b1.x); bvv[5]=(short)f2b(b1.y); bvv[6]=(short)f2b(b1.z); bvv[7]=(short)f2b(b1.w);
    *(u16x8*)&As[r*40 + c8] = a8;
    *(bf16x8*)&Bs[r*40 + c8] = bvv;
    __syncthreads();
    bf16x8 af = *(bf16x8*)&As[(w*16 + l15)*40 + l16*8];
#pragma unroll
    for (int nt = 0; nt < 4; nt++){
      bf16x8 bfr = *(bf16x8*)&Bs[(nt*16 + l15)*40 + l16*8];
      acc[nt] = __builtin_amdgcn_mfma_f32_16x16x32_bf16(af, bfr, acc[nt], 0, 0, 0);
    }
  }

#pragma unroll
  for (int j = 0; j < 4; j++){
    int grow = bm*64 + w*16 + l16*4 + j;
    float* dst = out + (size_t)grow*HID + bn*64;
#pragma unroll
    for (int nt = 0; nt < 4; nt++)
      dst[nt*16 + l15] = acc[nt][j];
  }
}

extern "C" void kernel_launch(void* const* d_in, const int* in_sizes, int n_in,
                              void* d_out, int out_size, void* d_ws, size_t ws_size,
                              hipStream_t stream)
{
  const float* hidden = (const float*)d_in[0];
  const int*   pos    = (const int*)d_in[1];
  const float* Wq = (const float*)d_in[2]; const float* bq = (const float*)d_in[3];
  const float* Wk = (const float*)d_in[4]; const float* bk = (const float*)d_in[5];
  const float* Wv = (const float*)d_in[6]; const float* bv = (const float*)d_in[7];
  const float* Wo = (const float*)d_in[8];

  unsigned short* qws  = (unsigned short*)d_ws;                      // (B,NH,S,64) bf16
  unsigned short* kws  = qws + (size_t)BT*NH*SEQ*64;                 // (B,NKV,S,64) bf16
  unsigned short* vtws = kws + (size_t)BT*NKV*SEQ*64;                // (B,NKV,S/64,64,64) f16 V^T tiles
  unsigned short* aws  = vtws + (size_t)BT*NKV*SEQ*64;               // (B,S,896) bf16

  qkv_rope_kernel<<<dim3(NTOK/64, 18), 256, 0, stream>>>(
      hidden, pos, Wq, bq, Wk, bk, Wv, bv, qws, kws, vtws);
  attn_kernel<<<dim3(16, NH, BT), 256, 0, stream>>>(qws, kws, vtws, aws);
  out_gemm_kernel<<<dim3(NTOK/64, NH), 256, 0, stream>>>(aws, Wo, (float*)d_out);
}

// Round 5
// 181.613 us; speedup vs baseline: 2.5461x; 1.0273x over previous
//
#include <hip/hip_runtime.h>

#define HID 896
#define NH 14
#define NKV 2
#define NREP 7
#define SEQ 2048
#define BT 2
#define NTOK (BT*SEQ)
#define CSCALE 0.18033688011112042f   // (1/8) * log2(e)

typedef __attribute__((ext_vector_type(8))) short bf16x8;
typedef __attribute__((ext_vector_type(8))) unsigned short u16x8;
typedef __attribute__((ext_vector_type(4))) float fx4;
typedef __attribute__((ext_vector_type(4))) short s16x4;
typedef _Float16 f16x4 __attribute__((ext_vector_type(4)));

__device__ __forceinline__ unsigned short f2b(float x){
  union { float f; unsigned u; } a; a.f = x;
  unsigned r = a.u + 0x7FFFu + ((a.u >> 16) & 1u);   // RNE
  return (unsigned short)(r >> 16);
}
__device__ __forceinline__ unsigned short f2h(float x){
  union { _Float16 h; unsigned short u; } a; a.h = (_Float16)x; return a.u;
}

// ---------------- fp32 -> bf16 convert (5 jobs via blockIdx.y) ----------------
__global__ __launch_bounds__(256) void cvt_kernel(
    const float* __restrict__ s0, const float* __restrict__ s1,
    const float* __restrict__ s2, const float* __restrict__ s3,
    const float* __restrict__ s4,
    unsigned short* __restrict__ d0, unsigned short* __restrict__ d1,
    unsigned short* __restrict__ d2, unsigned short* __restrict__ d3,
    unsigned short* __restrict__ d4,
    int c0, int c1, int c2, int c3, int c4)
{
  const float* s; unsigned short* d; int c;
  switch (blockIdx.y){
    case 0: s=s0; d=d0; c=c0; break;
    case 1: s=s1; d=d1; c=c1; break;
    case 2: s=s2; d=d2; c=c2; break;
    case 3: s=s3; d=d3; c=c3; break;
    default: s=s4; d=d4; c=c4; break;
  }
  for (int i = (blockIdx.x*256 + threadIdx.x)*8; i < c; i += gridDim.x*2048){
    float4 a = *(const float4*)(s + i);
    float4 b = *(const float4*)(s + i + 4);
    u16x8 o;
    o[0]=f2b(a.x); o[1]=f2b(a.y); o[2]=f2b(a.z); o[3]=f2b(a.w);
    o[4]=f2b(b.x); o[5]=f2b(b.y); o[6]=f2b(b.z); o[7]=f2b(b.w);
    *(u16x8*)(d + i) = o;
  }
}

// ---------------- QKV projection GEMM (128x128 tile) + bias + RoPE epilogue ----------------
// A = hidden bf16 [4096,896], B = WQKV bf16 [1152,896]. grid (32, 9), block 256 (4 waves 2x2).
// Head-units of 64 cols: hu = bn*2 + wn; hu<14 -> Q head hu; 14,15 -> K; 16,17 -> V.
__global__ __launch_bounds__(256) void qkv_gemm_kernel(
    const unsigned short* __restrict__ A, const unsigned short* __restrict__ Bw,
    const float* __restrict__ bq, const float* __restrict__ bk, const float* __restrict__ bv,
    const int* __restrict__ pos,
    unsigned short* __restrict__ qo, unsigned short* __restrict__ ko,
    unsigned short* __restrict__ vt)
{
  __shared__ short As[128*72];
  __shared__ short Bs[128*72];
  const int tid = threadIdx.x;
  const int bm = blockIdx.x, bn = blockIdx.y;
  const int w = tid >> 6, l = tid & 63, l15 = l & 15, q4 = l >> 4;
  const int wm = w & 1, wn = w >> 1;

  fx4 acc[4][4] = {};

  const int srow = tid >> 3, scol = (tid & 7)*8;
  const unsigned short* Ag = A  + (size_t)(bm*128 + srow)*HID + scol;
  const unsigned short* Bg = Bw + (size_t)(bn*128 + srow)*HID + scol;

  u16x8 ar[4], br[4];
#pragma unroll
  for (int p = 0; p < 4; p++){
    ar[p] = *(const u16x8*)(Ag + (size_t)p*32*HID);
    br[p] = *(const u16x8*)(Bg + (size_t)p*32*HID);
  }

  for (int kt = 0; kt < 14; kt++){
#pragma unroll
    for (int p = 0; p < 4; p++){
      *(u16x8*)&As[(srow + p*32)*72 + scol] = ar[p];
      *(u16x8*)&Bs[(srow + p*32)*72 + scol] = br[p];
    }
    __syncthreads();
    if (kt < 13){
      const int ko_ = (kt+1)*64;
#pragma unroll
      for (int p = 0; p < 4; p++){
        ar[p] = *(const u16x8*)(Ag + (size_t)p*32*HID + ko_);
        br[p] = *(const u16x8*)(Bg + (size_t)p*32*HID + ko_);
      }
    }
#pragma unroll
    for (int ks = 0; ks < 2; ks++){
      bf16x8 af[4], bf[4];
#pragma unroll
      for (int mt = 0; mt < 4; mt++)
        af[mt] = *(bf16x8*)&As[(wm*64 + mt*16 + l15)*72 + ks*32 + q4*8];
#pragma unroll
      for (int nt = 0; nt < 4; nt++)
        bf[nt] = *(bf16x8*)&Bs[(wn*64 + nt*16 + l15)*72 + ks*32 + q4*8];
#pragma unroll
      for (int mt = 0; mt < 4; mt++)
#pragma unroll
        for (int nt = 0; nt < 4; nt++)
          acc[mt][nt] = __builtin_amdgcn_mfma_f32_16x16x32_bf16(af[mt], bf[nt], acc[mt][nt], 0,0,0);
    }
    __syncthreads();
  }

  const int hu = bn*2 + wn;
  const float* bias; int kind, hloc;
  if (hu < NH)      { bias = bq + hu*64;      kind = 0; hloc = hu; }
  else if (hu < 16) { bias = bk + (hu-NH)*64; kind = 1; hloc = hu-NH; }
  else              { bias = bv + (hu-16)*64; kind = 2; hloc = hu-16; }
  float bl[4];
#pragma unroll
  for (int nt = 0; nt < 4; nt++) bl[nt] = bias[nt*16 + l15];

  if (kind == 2){
#pragma unroll
    for (int mt = 0; mt < 4; mt++)
#pragma unroll
      for (int j = 0; j < 4; j++){
        int grow = bm*128 + wm*64 + mt*16 + q4*4 + j;
        int b = grow >> 11, s = grow & (SEQ-1);
        int tile = s >> 6, key = s & 63;
        unsigned short* dst = vt + (size_t)(((b*NKV + hloc)*(SEQ/64) + tile)*4096);
#pragma unroll
        for (int nt = 0; nt < 4; nt++)
          dst[(nt*16 + l15)*64 + key] = f2h(acc[mt][nt][j] + bl[nt]);
      }
  } else {
    float invf[2];
#pragma unroll
    for (int nt = 0; nt < 2; nt++)
      invf[nt] = exp2f(-(float)(nt*16 + l15) * 0.62286151779138041f);
#pragma unroll
    for (int mt = 0; mt < 4; mt++)
#pragma unroll
      for (int j = 0; j < 4; j++){
        int grow = bm*128 + wm*64 + mt*16 + q4*4 + j;
        int b = grow >> 11, s = grow & (SEQ-1);
        float p = (float)pos[grow];
        unsigned short* dst = (kind == 0)
            ? qo + ((size_t)(b*NH  + hloc)*SEQ + s)*64
            : ko + ((size_t)(b*NKV + hloc)*SEQ + s)*64;
#pragma unroll
        for (int nt = 0; nt < 2; nt++){
          int d = nt*16 + l15;
          float f = p * invf[nt];
          float sv, cv;
          sincosf(f, &sv, &cv);
          float x1 = acc[mt][nt][j]   + bl[nt];
          float x2 = acc[mt][nt+2][j] + bl[nt+2];
          dst[d]    = f2b(x1*cv - x2*sv);
          dst[d+32] = f2b(x2*cv + x1*sv);
        }
      }
  }
}

// -------- per-tile softmax + PV update (S^T orientation; verified R3/R4) --------
__device__ __forceinline__ void smax_pv(
    const fx4* s, bool diag, int wl, int q4,
    float& m_run, float& l_run, fx4* o, const f16x4 vf[4][4])
{
  float tv[16];
#pragma unroll
  for (int tl = 0; tl < 4; tl++)
#pragma unroll
    for (int j = 0; j < 4; j++){
      float x = s[tl][j]*CSCALE;
      if (diag && (tl*16 + q4*4 + j > wl)) x = -1e30f;
      tv[tl*4+j] = x;
    }
  float mx = tv[0];
#pragma unroll
  for (int i = 1; i < 16; i++) mx = fmaxf(mx, tv[i]);
  mx = fmaxf(mx, __shfl_xor(mx, 16));
  mx = fmaxf(mx, __shfl_xor(mx, 32));
  float mn = fmaxf(m_run, mx);
  float al = exp2f(m_run - mn);
  m_run = mn;
  float p[16], rs = 0.f;
#pragma unroll
  for (int i = 0; i < 16; i++){ p[i] = exp2f(tv[i] - mn); rs += p[i]; }
  rs += __shfl_xor(rs, 16);
  rs += __shfl_xor(rs, 32);
  l_run = l_run*al + rs;
#pragma unroll
  for (int nt = 0; nt < 4; nt++)
#pragma unroll
    for (int j = 0; j < 4; j++) o[nt][j] *= al;
  f16x4 pf[4];
#pragma unroll
  for (int tl = 0; tl < 4; tl++){
    pf[tl][0] = (_Float16)p[tl*4+0];
    pf[tl][1] = (_Float16)p[tl*4+1];
    pf[tl][2] = (_Float16)p[tl*4+2];
    pf[tl][3] = (_Float16)p[tl*4+3];
  }
#pragma unroll
  for (int nt = 0; nt < 4; nt++)
#pragma unroll
    for (int tl = 0; tl < 4; tl++)
      o[nt] = __builtin_amdgcn_mfma_f32_16x16x16f16(vf[nt][tl], pf[tl], o[nt], 0,0,0);
}

// ---------------- flash attention v4 (unchanged from R4; verified) ----------------
__global__ __launch_bounds__(256) void attn_kernel(
    const unsigned short* __restrict__ q, const unsigned short* __restrict__ k,
    const unsigned short* __restrict__ vt, unsigned short* __restrict__ ao)
{
  __shared__ short Ks[64*72];
  __shared__ short Vt[64*72];

  const int tid = threadIdx.x;
  const int w = tid >> 6, l = tid & 63, l15 = l & 15, q4 = l >> 4;
  const int tlo = blockIdx.x, thi = 31 - tlo;
  const int h = blockIdx.y, b = blockIdx.z, kvh = h / NREP;
  const int wl = w*16 + l15;

  const unsigned short* qbase = q + ((size_t)(b*NH + h)*SEQ)*64;
  const unsigned short* qpA = qbase + (size_t)(thi*64 + wl)*64;
  const unsigned short* qpB = qbase + (size_t)(tlo*64 + wl)*64;
  bf16x8 qA0 = *(const bf16x8*)(qpA + q4*8), qA1 = *(const bf16x8*)(qpA + 32 + q4*8);
  bf16x8 qB0 = *(const bf16x8*)(qpB + q4*8), qB1 = *(const bf16x8*)(qpB + 32 + q4*8);

  fx4 oA[4] = {{0,0,0,0},{0,0,0,0},{0,0,0,0},{0,0,0,0}};
  fx4 oB[4] = {{0,0,0,0},{0,0,0,0},{0,0,0,0},{0,0,0,0}};
  float mA = -1e30f, lA = 0.f, mB = -1e30f, lB = 0.f;

  const unsigned short* kbase = k  + ((size_t)(b*NKV + kvh)*SEQ)*64;
  const unsigned short* vbase = vt + (size_t)((b*NKV + kvh)*(SEQ/64))*4096;

  u16x8 kreg[2], vreg[2];
#pragma unroll
  for (int p = 0; p < 2; p++){
    int n = p*256 + tid;
    kreg[p] = *(const u16x8*)(kbase + n*8);
    vreg[p] = *(const u16x8*)(vbase + n*8);
  }

  for (int kt = 0; kt <= thi; kt++){
#pragma unroll
    for (int p = 0; p < 2; p++){
      int n = p*256 + tid, rr = n >> 3, g = n & 7;
      *(u16x8*)&Ks[rr*72 + g*8] = kreg[p];
      *(u16x8*)&Vt[rr*72 + g*8] = vreg[p];
    }
    __syncthreads();

    if (kt < thi){
      const unsigned short* kn = kbase + (size_t)(kt+1)*4096;
      const unsigned short* vn = vbase + (size_t)(kt+1)*4096;
#pragma unroll
      for (int p = 0; p < 2; p++){
        int n = p*256 + tid;
        kreg[p] = *(const u16x8*)(kn + n*8);
        vreg[p] = *(const u16x8*)(vn + n*8);
      }
    }

    bf16x8 kf0[4], kf1[4];
#pragma unroll
    for (int tl = 0; tl < 4; tl++){
      kf0[tl] = *(bf16x8*)&Ks[(tl*16 + l15)*72 + q4*8];
      kf1[tl] = *(bf16x8*)&Ks[(tl*16 + l15)*72 + 32 + q4*8];
    }
    f16x4 vf[4][4];
#pragma unroll
    for (int nt = 0; nt < 4; nt++)
#pragma unroll
      for (int tl = 0; tl < 4; tl++)
        vf[nt][tl] = *(f16x4*)&Vt[(nt*16 + l15)*72 + tl*16 + q4*4];

    {
      fx4 s[4] = {{0,0,0,0},{0,0,0,0},{0,0,0,0},{0,0,0,0}};
#pragma unroll
      for (int tl = 0; tl < 4; tl++){
        s[tl] = __builtin_amdgcn_mfma_f32_16x16x32_bf16(kf0[tl], qA0, s[tl], 0,0,0);
        s[tl] = __builtin_amdgcn_mfma_f32_16x16x32_bf16(kf1[tl], qA1, s[tl], 0,0,0);
      }
      smax_pv(s, kt == thi, wl, q4, mA, lA, oA, vf);
    }
    if (kt <= tlo){
      fx4 s[4] = {{0,0,0,0},{0,0,0,0},{0,0,0,0},{0,0,0,0}};
#pragma unroll
      for (int tl = 0; tl < 4; tl++){
        s[tl] = __builtin_amdgcn_mfma_f32_16x16x32_bf16(kf0[tl], qB0, s[tl], 0,0,0);
        s[tl] = __builtin_amdgcn_mfma_f32_16x16x32_bf16(kf1[tl], qB1, s[tl], 0,0,0);
      }
      smax_pv(s, kt == tlo, wl, q4, mB, lB, oB, vf);
    }
    __syncthreads();
  }

  {
    float inv = 1.0f / lA;
    unsigned short* dst = ao + ((size_t)(b*SEQ + thi*64 + wl))*HID + h*64;
#pragma unroll
    for (int nt = 0; nt < 4; nt++){
      s16x4 ov;
      ov[0] = (short)f2b(oA[nt][0]*inv); ov[1] = (short)f2b(oA[nt][1]*inv);
      ov[2] = (short)f2b(oA[nt][2]*inv); ov[3] = (short)f2b(oA[nt][3]*inv);
      *(s16x4*)(dst + nt*16 + q4*4) = ov;
    }
  }
  {
    float inv = 1.0f / lB;
    unsigned short* dst = ao + ((size_t)(b*SEQ + tlo*64 + wl))*HID + h*64;
#pragma unroll
    for (int nt = 0; nt < 4; nt++){
      s16x4 ov;
      ov[0] = (short)f2b(oB[nt][0]*inv); ov[1] = (short)f2b(oB[nt][1]*inv);
      ov[2] = (short)f2b(oB[nt][2]*inv); ov[3] = (short)f2b(oB[nt][3]*inv);
      *(s16x4*)(dst + nt*16 + q4*4) = ov;
    }
  }
}

// ---------------- output projection GEMM (128x128 tile) -> fp32 ----------------
// A = attn bf16 [4096,896], B = Wo bf16 [896,896]. grid (32, 7), block 256.
__global__ __launch_bounds__(256) void out_gemm_kernel(
    const unsigned short* __restrict__ A, const unsigned short* __restrict__ Bw,
    float* __restrict__ out)
{
  __shared__ short As[128*72];
  __shared__ short Bs[128*72];
  const int tid = threadIdx.x;
  const int bm = blockIdx.x, bn = blockIdx.y;
  const int w = tid >> 6, l = tid & 63, l15 = l & 15, q4 = l >> 4;
  const int wm = w & 1, wn = w >> 1;

  fx4 acc[4][4] = {};

  const int srow = tid >> 3, scol = (tid & 7)*8;
  const unsigned short* Ag = A  + (size_t)(bm*128 + srow)*HID + scol;
  const unsigned short* Bg = Bw + (size_t)(bn*128 + srow)*HID + scol;

  u16x8 ar[4], br[4];
#pragma unroll
  for (int p = 0; p < 4; p++){
    ar[p] = *(const u16x8*)(Ag + (size_t)p*32*HID);
    br[p] = *(const u16x8*)(Bg + (size_t)p*32*HID);
  }

  for (int kt = 0; kt < 14; kt++){
#pragma unroll
    for (int p = 0; p < 4; p++){
      *(u16x8*)&As[(srow + p*32)*72 + scol] = ar[p];
      *(u16x8*)&Bs[(srow + p*32)*72 + scol] = br[p];
    }
    __syncthreads();
    if (kt < 13){
      const int ko_ = (kt+1)*64;
#pragma unroll
      for (int p = 0; p < 4; p++){
        ar[p] = *(const u16x8*)(Ag + (size_t)p*32*HID + ko_);
        br[p] = *(const u16x8*)(Bg + (size_t)p*32*HID + ko_);
      }
    }
#pragma unroll
    for (int ks = 0; ks < 2; ks++){
      bf16x8 af[4], bf[4];
#pragma unroll
      for (int mt = 0; mt < 4; mt++)
        af[mt] = *(bf16x8*)&As[(wm*64 + mt*16 + l15)*72 + ks*32 + q4*8];
#pragma unroll
      for (int nt = 0; nt < 4; nt++)
        bf[nt] = *(bf16x8*)&Bs[(wn*64 + nt*16 + l15)*72 + ks*32 + q4*8];
#pragma unroll
      for (int mt = 0; mt < 4; mt++)
#pragma unroll
        for (int nt = 0; nt < 4; nt++)
          acc[mt][nt] = __builtin_amdgcn_mfma_f32_16x16x32_bf16(af[mt], bf[nt], acc[mt][nt], 0,0,0);
    }
    __syncthreads();
  }

#pragma unroll
  for (int mt = 0; mt < 4; mt++)
#pragma unroll
    for (int j = 0; j < 4; j++){
      int grow = bm*128 + wm*64 + mt*16 + q4*4 + j;
      float* dst = out + (size_t)grow*HID + bn*128 + wn*64;
#pragma unroll
      for (int nt = 0; nt < 4; nt++)
        dst[nt*16 + l15] = acc[mt][nt][j];
    }
}

extern "C" void kernel_launch(void* const* d_in, const int* in_sizes, int n_in,
                              void* d_out, int out_size, void* d_ws, size_t ws_size,
                              hipStream_t stream)
{
  const float* hidden = (const float*)d_in[0];
  const int*   pos    = (const int*)d_in[1];
  const float* Wq = (const float*)d_in[2]; const float* bq = (const float*)d_in[3];
  const float* Wk = (const float*)d_in[4]; const float* bk = (const float*)d_in[5];
  const float* Wv = (const float*)d_in[6]; const float* bv = (const float*)d_in[7];
  const float* Wo = (const float*)d_in[8];

  // workspace layout (shorts). h16 (hidden bf16) aliases aws (attn out) — disjoint lifetimes.
  unsigned short* qws   = (unsigned short*)d_ws;                       // 3,670,016  (B,NH,S,64)
  unsigned short* kws   = qws   + (size_t)BT*NH*SEQ*64;                //   524,288  (B,NKV,S,64)
  unsigned short* vtws  = kws   + (size_t)BT*NKV*SEQ*64;               //   524,288  (B,NKV,S/64,64,64) f16
  unsigned short* wqkv  = vtws  + (size_t)BT*NKV*SEQ*64;               // 1,032,192  (1152,896)
  unsigned short* wo16  = wqkv  + (size_t)(NH+2*NKV/2)*0 + 1152*HID;   //   802,816  (896,896)
  unsigned short* h16   = wo16  + (size_t)HID*HID;                     // 3,670,016  (4096,896) == aws

  const int nh   = NTOK*HID;        // 3,670,016
  const int nwq  = HID*HID;         //   802,816
  const int nwkv = 2*64*HID;        //   114,688

  cvt_kernel<<<dim3(448, 5), 256, 0, stream>>>(
      hidden, Wq, Wk, Wv, Wo,
      h16, wqkv, wqkv + nwq, wqkv + nwq + nwkv, wo16,
      nh, nwq, nwkv, nwkv, nwq);

  qkv_gemm_kernel<<<dim3(NTOK/128, 9), 256, 0, stream>>>(
      h16, wqkv, bq, bk, bv, pos, qws, kws, vtws);

  attn_kernel<<<dim3(16, NH, BT), 256, 0, stream>>>(qws, kws, vtws, h16 /*aws*/);

  out_gemm_kernel<<<dim3(NTOK/128, 7), 256, 0, stream>>>(h16 /*aws*/, wo16, (float*)d_out);
}

// Round 7
// 171.729 us; speedup vs baseline: 2.6926x; 1.0576x over previous
//
#include <hip/hip_runtime.h>

#define HID 896
#define NH 14
#define NKV 2
#define NREP 7
#define SEQ 2048
#define BT 2
#define NTOK (BT*SEQ)
#define CSCALE 0.18033688011112042f   // (1/8) * log2(e)

typedef __attribute__((ext_vector_type(8))) short bf16x8;
typedef __attribute__((ext_vector_type(8))) unsigned short u16x8;
typedef __attribute__((ext_vector_type(4))) float fx4;
typedef __attribute__((ext_vector_type(4))) short s16x4;
typedef _Float16 f16x4 __attribute__((ext_vector_type(4)));
typedef __fp16 fp16x2 __attribute__((ext_vector_type(2)));   // matches cvt_pkrtz return type

__device__ __forceinline__ unsigned short f2b(float x){
  union { float f; unsigned u; } a; a.f = x;
  unsigned r = a.u + 0x7FFFu + ((a.u >> 16) & 1u);   // RNE
  return (unsigned short)(r >> 16);
}
__device__ __forceinline__ unsigned short f2h(float x){
  union { _Float16 h; unsigned short u; } a; a.h = (_Float16)x; return a.u;
}

// ---------------- fp32 -> bf16 convert (5 jobs via blockIdx.y) ----------------
__global__ __launch_bounds__(256) void cvt_kernel(
    const float* __restrict__ s0, const float* __restrict__ s1,
    const float* __restrict__ s2, const float* __restrict__ s3,
    const float* __restrict__ s4,
    unsigned short* __restrict__ d0, unsigned short* __restrict__ d1,
    unsigned short* __restrict__ d2, unsigned short* __restrict__ d3,
    unsigned short* __restrict__ d4,
    int c0, int c1, int c2, int c3, int c4)
{
  const float* s; unsigned short* d; int c;
  switch (blockIdx.y){
    case 0: s=s0; d=d0; c=c0; break;
    case 1: s=s1; d=d1; c=c1; break;
    case 2: s=s2; d=d2; c=c2; break;
    case 3: s=s3; d=d3; c=c3; break;
    default: s=s4; d=d4; c=c4; break;
  }
  for (int i = (blockIdx.x*256 + threadIdx.x)*8; i < c; i += gridDim.x*2048){
    float4 a = *(const float4*)(s + i);
    float4 b = *(const float4*)(s + i + 4);
    u16x8 o;
    o[0]=f2b(a.x); o[1]=f2b(a.y); o[2]=f2b(a.z); o[3]=f2b(a.w);
    o[4]=f2b(b.x); o[5]=f2b(b.y); o[6]=f2b(b.z); o[7]=f2b(b.w);
    *(u16x8*)(d + i) = o;
  }
}

// ---------------- QKV projection GEMM (64x128 tile, 2x2 waves) + bias + RoPE ----------------
// A = hidden bf16 [4096,896], B = WQKV bf16 [1152,896]. grid (64, 9), block 256.
// wm = w>>1 (32-row half), wn = w&1 (64-col half). Head-unit hu = bn*2 + wn.
__global__ __launch_bounds__(256) void qkv_gemm_kernel(
    const unsigned short* __restrict__ A, const unsigned short* __restrict__ Bw,
    const float* __restrict__ bq, const float* __restrict__ bk, const float* __restrict__ bv,
    const int* __restrict__ pos,
    unsigned short* __restrict__ qo, unsigned short* __restrict__ ko,
    unsigned short* __restrict__ vt)
{
  __shared__ short As[64*72];
  __shared__ short Bs[128*72];
  const int tid = threadIdx.x;
  const int bm = blockIdx.x, bn = blockIdx.y;
  const int w = tid >> 6, l = tid & 63, l15 = l & 15, q4 = l >> 4;
  const int wm = w >> 1, wn = w & 1;

  fx4 acc[2][4] = {};

  const int srow = tid >> 3, scol = (tid & 7)*8;   // srow 0..31
  const unsigned short* Ag = A  + (size_t)(bm*64  + srow)*HID + scol;
  const unsigned short* Bg = Bw + (size_t)(bn*128 + srow)*HID + scol;

  u16x8 ar[2], br[4];
#pragma unroll
  for (int p = 0; p < 2; p++) ar[p] = *(const u16x8*)(Ag + (size_t)p*32*HID);
#pragma unroll
  for (int p = 0; p < 4; p++) br[p] = *(const u16x8*)(Bg + (size_t)p*32*HID);

  for (int kt = 0; kt < 14; kt++){
#pragma unroll
    for (int p = 0; p < 2; p++) *(u16x8*)&As[(srow + p*32)*72 + scol] = ar[p];
#pragma unroll
    for (int p = 0; p < 4; p++) *(u16x8*)&Bs[(srow + p*32)*72 + scol] = br[p];
    __syncthreads();
    if (kt < 13){
      const int ko_ = (kt+1)*64;
#pragma unroll
      for (int p = 0; p < 2; p++) ar[p] = *(const u16x8*)(Ag + (size_t)p*32*HID + ko_);
#pragma unroll
      for (int p = 0; p < 4; p++) br[p] = *(const u16x8*)(Bg + (size_t)p*32*HID + ko_);
    }
#pragma unroll
    for (int ks = 0; ks < 2; ks++){
      bf16x8 af[2], bf[4];
#pragma unroll
      for (int mt = 0; mt < 2; mt++)
        af[mt] = *(bf16x8*)&As[(wm*32 + mt*16 + l15)*72 + ks*32 + q4*8];
#pragma unroll
      for (int nt = 0; nt < 4; nt++)
        bf[nt] = *(bf16x8*)&Bs[(wn*64 + nt*16 + l15)*72 + ks*32 + q4*8];
#pragma unroll
      for (int mt = 0; mt < 2; mt++)
#pragma unroll
        for (int nt = 0; nt < 4; nt++)
          acc[mt][nt] = __builtin_amdgcn_mfma_f32_16x16x32_bf16(af[mt], bf[nt], acc[mt][nt], 0,0,0);
    }
    __syncthreads();
  }

  const int hu = bn*2 + wn;
  const float* bias; int kind, hloc;
  if (hu < NH)      { bias = bq + hu*64;      kind = 0; hloc = hu; }
  else if (hu < 16) { bias = bk + (hu-NH)*64; kind = 1; hloc = hu-NH; }
  else              { bias = bv + (hu-16)*64; kind = 2; hloc = hu-16; }
  float bl[4];
#pragma unroll
  for (int nt = 0; nt < 4; nt++) bl[nt] = bias[nt*16 + l15];

  if (kind == 2){
#pragma unroll
    for (int mt = 0; mt < 2; mt++)
#pragma unroll
      for (int j = 0; j < 4; j++){
        int grow = bm*64 + wm*32 + mt*16 + q4*4 + j;
        int b = grow >> 11, s = grow & (SEQ-1);
        int tile = s >> 6, key = s & 63;
        unsigned short* dst = vt + (size_t)(((b*NKV + hloc)*(SEQ/64) + tile)*4096);
#pragma unroll
        for (int nt = 0; nt < 4; nt++)
          dst[(nt*16 + l15)*64 + key] = f2h(acc[mt][nt][j] + bl[nt]);
      }
  } else {
    float invf[2];
#pragma unroll
    for (int nt = 0; nt < 2; nt++)
      invf[nt] = exp2f(-(float)(nt*16 + l15) * 0.62286151779138041f);
#pragma unroll
    for (int mt = 0; mt < 2; mt++)
#pragma unroll
      for (int j = 0; j < 4; j++){
        int grow = bm*64 + wm*32 + mt*16 + q4*4 + j;
        int b = grow >> 11, s = grow & (SEQ-1);
        float p = (float)pos[grow];
        unsigned short* dst = (kind == 0)
            ? qo + ((size_t)(b*NH  + hloc)*SEQ + s)*64
            : ko + ((size_t)(b*NKV + hloc)*SEQ + s)*64;
#pragma unroll
        for (int nt = 0; nt < 2; nt++){
          int d = nt*16 + l15;
          float f = p * invf[nt];
          float sv, cv;
          sincosf(f, &sv, &cv);
          float x1 = acc[mt][nt][j]   + bl[nt];
          float x2 = acc[mt][nt+2][j] + bl[nt+2];
          dst[d]    = f2b(x1*cv - x2*sv);
          dst[d+32] = f2b(x2*cv + x1*sv);
        }
      }
  }
}

// -------- per-tile softmax + PV update (S^T orientation; verified R3-R5) --------
__device__ __forceinline__ void smax_pv(
    const fx4* s, bool diag, int wl, int q4,
    float& m_run, float& l_run, fx4* o, const f16x4 vf[4][4])
{
  float tv[16];
#pragma unroll
  for (int tl = 0; tl < 4; tl++)
#pragma unroll
    for (int j = 0; j < 4; j++){
      float x = s[tl][j]*CSCALE;
      if (diag && (tl*16 + q4*4 + j > wl)) x = -1e30f;
      tv[tl*4+j] = x;
    }
  float mx = tv[0];
#pragma unroll
  for (int i = 1; i < 16; i++) mx = fmaxf(mx, tv[i]);
  mx = fmaxf(mx, __shfl_xor(mx, 16));
  mx = fmaxf(mx, __shfl_xor(mx, 32));
  float mn = fmaxf(m_run, mx);
  float al = exp2f(m_run - mn);
  m_run = mn;
  float p[16], rs = 0.f;
#pragma unroll
  for (int i = 0; i < 16; i++){ p[i] = exp2f(tv[i] - mn); rs += p[i]; }
  rs += __shfl_xor(rs, 16);
  rs += __shfl_xor(rs, 32);
  l_run = l_run*al + rs;
#pragma unroll
  for (int nt = 0; nt < 4; nt++)
#pragma unroll
    for (int j = 0; j < 4; j++) o[nt][j] *= al;
  f16x4 pf[4];
#pragma unroll
  for (int tl = 0; tl < 4; tl++){
    union { f16x4 v; fp16x2 h[2]; } u;
    u.h[0] = __builtin_amdgcn_cvt_pkrtz(p[tl*4+0], p[tl*4+1]);
    u.h[1] = __builtin_amdgcn_cvt_pkrtz(p[tl*4+2], p[tl*4+3]);
    pf[tl] = u.v;
  }
#pragma unroll
  for (int nt = 0; nt < 4; nt++)
#pragma unroll
    for (int tl = 0; tl < 4; tl++)
      o[nt] = __builtin_amdgcn_mfma_f32_16x16x16f16(vf[nt][tl], pf[tl], o[nt], 0,0,0);
}

// ---------------- flash attention v5: split-K wave groups ----------------
// grid (16, NH, BT), block 512 (8 waves). Group g = w>>2 handles k-tiles with parity g
// (independent online-softmax states, merged exactly at the end via LDS).
// Block covers q-tiles tlo=bx and thi=31-bx; wave wi owns 16 q-rows of each.
__global__ __launch_bounds__(512) void attn_kernel(
    const unsigned short* __restrict__ q, const unsigned short* __restrict__ k,
    const unsigned short* __restrict__ vt, unsigned short* __restrict__ ao)
{
  __shared__ short SB[4*64*72];            // Ks[2] | Vt[2]; reused as merge buffer (36,864B)
  short* KsB = SB;                         // KsB + tile*4608
  short* VtB = SB + 2*64*72;

  const int tid = threadIdx.x;
  const int w = tid >> 6, l = tid & 63, l15 = l & 15, q4 = l >> 4;
  const int g = w >> 2, wi = w & 3;
  const int tlo = blockIdx.x, thi = 31 - tlo;
  const int h = blockIdx.y, b = blockIdx.z, kvh = h / NREP;
  const int wl = wi*16 + l15;

  const unsigned short* qbase = q + ((size_t)(b*NH + h)*SEQ)*64;
  const unsigned short* qpA = qbase + (size_t)(thi*64 + wl)*64;
  const unsigned short* qpB = qbase + (size_t)(tlo*64 + wl)*64;
  bf16x8 qA0 = *(const bf16x8*)(qpA + q4*8), qA1 = *(const bf16x8*)(qpA + 32 + q4*8);
  bf16x8 qB0 = *(const bf16x8*)(qpB + q4*8), qB1 = *(const bf16x8*)(qpB + 32 + q4*8);

  fx4 oA[4] = {}, oB[4] = {};
  float mA = -1e30f, lA = 0.f, mB = -1e30f, lB = 0.f;

  const unsigned short* kbase = k  + ((size_t)(b*NKV + kvh)*SEQ)*64;
  const unsigned short* vbase = vt + (size_t)((b*NKV + kvh)*(SEQ/64))*4096;

  const int P = (thi + 2) >> 1;            // number of tile pairs

  // staging: thread covers chunks idx = p*512+tid of the 2-tile pair (8 shorts each)
  u16x8 kreg[2], vreg[2];
#pragma unroll
  for (int p = 0; p < 2; p++){
    int idx = p*512 + tid, tile = idx >> 9, off = idx & 511;
    kreg[p] = *(const u16x8*)(kbase + (size_t)tile*4096 + off*8);
    vreg[p] = *(const u16x8*)(vbase + (size_t)tile*4096 + off*8);
  }

  for (int si = 0; si < P; si++){
#pragma unroll
    for (int p = 0; p < 2; p++){
      int idx = p*512 + tid, tile = idx >> 9, off = idx & 511;
      int rr = off >> 3, g8 = off & 7;
      *(u16x8*)&KsB[tile*4608 + rr*72 + g8*8] = kreg[p];
      *(u16x8*)&VtB[tile*4608 + rr*72 + g8*8] = vreg[p];
    }
    __syncthreads();

    if (si + 1 < P){
      const int k0n = 2*(si+1);
#pragma unroll
      for (int p = 0; p < 2; p++){
        int idx = p*512 + tid, tile = idx >> 9, off = idx & 511;
        int tk = k0n + tile; if (tk > thi) tk = thi;
        kreg[p] = *(const u16x8*)(kbase + (size_t)tk*4096 + off*8);
        vreg[p] = *(const u16x8*)(vbase + (size_t)tk*4096 + off*8);
      }
    }

    const int kt = 2*si + g;
    if (kt <= thi){                       // wave-group-uniform
      const short* Kst = KsB + g*4608;
      const short* Vtt = VtB + g*4608;
      bf16x8 kf0[4], kf1[4];
#pragma unroll
      for (int tl = 0; tl < 4; tl++){
        kf0[tl] = *(const bf16x8*)&Kst[(tl*16 + l15)*72 + q4*8];
        kf1[tl] = *(const bf16x8*)&Kst[(tl*16 + l15)*72 + 32 + q4*8];
      }
      f16x4 vf[4][4];
#pragma unroll
      for (int nt = 0; nt < 4; nt++)
#pragma unroll
        for (int tl = 0; tl < 4; tl++)
          vf[nt][tl] = *(const f16x4*)&Vtt[(nt*16 + l15)*72 + tl*16 + q4*4];

      {
        fx4 s[4] = {};
#pragma unroll
        for (int tl = 0; tl < 4; tl++){
          s[tl] = __builtin_amdgcn_mfma_f32_16x16x32_bf16(kf0[tl], qA0, s[tl], 0,0,0);
          s[tl] = __builtin_amdgcn_mfma_f32_16x16x32_bf16(kf1[tl], qA1, s[tl], 0,0,0);
        }
        smax_pv(s, kt == thi, wl, q4, mA, lA, oA, vf);
      }
      if (kt <= tlo){
        fx4 s[4] = {};
#pragma unroll
        for (int tl = 0; tl < 4; tl++){
          s[tl] = __builtin_amdgcn_mfma_f32_16x16x32_bf16(kf0[tl], qB0, s[tl], 0,0,0);
          s[tl] = __builtin_amdgcn_mfma_f32_16x16x32_bf16(kf1[tl], qB1, s[tl], 0,0,0);
        }
        smax_pv(s, kt == tlo, wl, q4, mB, lB, oB, vf);
      }
    }
    __syncthreads();
  }

  // ---- merge group 1 into group 0 via LDS (exact, fp32) ----
  float* F = (float*)SB;                  // [wi*2+ab][lane][18]
  if (g == 1){
    float* fa = F + (((wi*2 + 0)*64 + l)*18);
#pragma unroll
    for (int nt = 0; nt < 4; nt++)
#pragma unroll
      for (int j = 0; j < 4; j++) fa[nt*4 + j] = oA[nt][j];
    fa[16] = mA; fa[17] = lA;
    float* fb = F + (((wi*2 + 1)*64 + l)*18);
#pragma unroll
    for (int nt = 0; nt < 4; nt++)
#pragma unroll
      for (int j = 0; j < 4; j++) fb[nt*4 + j] = oB[nt][j];
    fb[16] = mB; fb[17] = lB;
  }
  __syncthreads();
  if (g == 0){
    {
      const float* fa = F + (((wi*2 + 0)*64 + l)*18);
      float m1 = fa[16], l1 = fa[17];
      float mM = fmaxf(mA, m1);
      float a0 = exp2f(mA - mM), a1 = exp2f(m1 - mM);
      lA = lA*a0 + l1*a1;
#pragma unroll
      for (int nt = 0; nt < 4; nt++)
#pragma unroll
        for (int j = 0; j < 4; j++) oA[nt][j] = oA[nt][j]*a0 + fa[nt*4+j]*a1;
    }
    {
      const float* fb = F + (((wi*2 + 1)*64 + l)*18);
      float m1 = fb[16], l1 = fb[17];
      float mM = fmaxf(mB, m1);
      float a0 = exp2f(mB - mM), a1 = exp2f(m1 - mM);
      lB = lB*a0 + l1*a1;
#pragma unroll
      for (int nt = 0; nt < 4; nt++)
#pragma unroll
        for (int j = 0; j < 4; j++) oB[nt][j] = oB[nt][j]*a0 + fb[nt*4+j]*a1;
    }
    {
      float inv = 1.0f / lA;
      unsigned short* dst = ao + ((size_t)(b*SEQ + thi*64 + wl))*HID + h*64;
#pragma unroll
      for (int nt = 0; nt < 4; nt++){
        s16x4 ov;
        ov[0] = (short)f2b(oA[nt][0]*inv); ov[1] = (short)f2b(oA[nt][1]*inv);
        ov[2] = (short)f2b(oA[nt][2]*inv); ov[3] = (short)f2b(oA[nt][3]*inv);
        *(s16x4*)(dst + nt*16 + q4*4) = ov;
      }
    }
    {
      float inv = 1.0f / lB;
      unsigned short* dst = ao + ((size_t)(b*SEQ + tlo*64 + wl))*HID + h*64;
#pragma unroll
      for (int nt = 0; nt < 4; nt++){
        s16x4 ov;
        ov[0] = (short)f2b(oB[nt][0]*inv); ov[1] = (short)f2b(oB[nt][1]*inv);
        ov[2] = (short)f2b(oB[nt][2]*inv); ov[3] = (short)f2b(oB[nt][3]*inv);
        *(s16x4*)(dst + nt*16 + q4*4) = ov;
      }
    }
  }
}

// ---------------- output projection GEMM (64x128 tile, 2x2 waves) -> fp32 ----------------
// A = attn bf16 [4096,896], B = Wo bf16 [896,896]. grid (64, 7), block 256.
__global__ __launch_bounds__(256) void out_gemm_kernel(
    const unsigned short* __restrict__ A, const unsigned short* __restrict__ Bw,
    float* __restrict__ out)
{
  __shared__ short As[64*72];
  __shared__ short Bs[128*72];
  const int tid = threadIdx.x;
  const int bm = blockIdx.x, bn = blockIdx.y;
  const int w = tid >> 6, l = tid & 63, l15 = l & 15, q4 = l >> 4;
  const int wm = w >> 1, wn = w & 1;

  fx4 acc[2][4] = {};

  const int srow = tid >> 3, scol = (tid & 7)*8;
  const unsigned short* Ag = A  + (size_t)(bm*64  + srow)*HID + scol;
  const unsigned short* Bg = Bw + (size_t)(bn*128 + srow)*HID + scol;

  u16x8 ar[2], br[4];
#pragma unroll
  for (int p = 0; p < 2; p++) ar[p] = *(const u16x8*)(Ag + (size_t)p*32*HID);
#pragma unroll
  for (int p = 0; p < 4; p++) br[p] = *(const u16x8*)(Bg + (size_t)p*32*HID);

  for (int kt = 0; kt < 14; kt++){
#pragma unroll
    for (int p = 0; p < 2; p++) *(u16x8*)&As[(srow + p*32)*72 + scol] = ar[p];
#pragma unroll
    for (int p = 0; p < 4; p++) *(u16x8*)&Bs[(srow + p*32)*72 + scol] = br[p];
    __syncthreads();
    if (kt < 13){
      const int ko_ = (kt+1)*64;
#pragma unroll
      for (int p = 0; p < 2; p++) ar[p] = *(const u16x8*)(Ag + (size_t)p*32*HID + ko_);
#pragma unroll
      for (int p = 0; p < 4; p++) br[p] = *(const u16x8*)(Bg + (size_t)p*32*HID + ko_);
    }
#pragma unroll
    for (int ks = 0; ks < 2; ks++){
      bf16x8 af[2], bf[4];
#pragma unroll
      for (int mt = 0; mt < 2; mt++)
        af[mt] = *(bf16x8*)&As[(wm*32 + mt*16 + l15)*72 + ks*32 + q4*8];
#pragma unroll
      for (int nt = 0; nt < 4; nt++)
        bf[nt] = *(bf16x8*)&Bs[(wn*64 + nt*16 + l15)*72 + ks*32 + q4*8];
#pragma unroll
      for (int mt = 0; mt < 2; mt++)
#pragma unroll
        for (int nt = 0; nt < 4; nt++)
          acc[mt][nt] = __builtin_amdgcn_mfma_f32_16x16x32_bf16(af[mt], bf[nt], acc[mt][nt], 0,0,0);
    }
    __syncthreads();
  }

#pragma unroll
  for (int mt = 0; mt < 2; mt++)
#pragma unroll
    for (int j = 0; j < 4; j++){
      int grow = bm*64 + wm*32 + mt*16 + q4*4 + j;
      float* dst = out + (size_t)grow*HID + bn*128 + wn*64;
#pragma unroll
      for (int nt = 0; nt < 4; nt++)
        dst[nt*16 + l15] = acc[mt][nt][j];
    }
}

extern "C" void kernel_launch(void* const* d_in, const int* in_sizes, int n_in,
                              void* d_out, int out_size, void* d_ws, size_t ws_size,
                              hipStream_t stream)
{
  const float* hidden = (const float*)d_in[0];
  const int*   pos    = (const int*)d_in[1];
  const float* Wq = (const float*)d_in[2]; const float* bq = (const float*)d_in[3];
  const float* Wk = (const float*)d_in[4]; const float* bk = (const float*)d_in[5];
  const float* Wv = (const float*)d_in[6]; const float* bv = (const float*)d_in[7];
  const float* Wo = (const float*)d_in[8];

  unsigned short* qws   = (unsigned short*)d_ws;                       // (B,NH,S,64) bf16
  unsigned short* kws   = qws   + (size_t)BT*NH*SEQ*64;                // (B,NKV,S,64) bf16
  unsigned short* vtws  = kws   + (size_t)BT*NKV*SEQ*64;               // (B,NKV,S/64,64,64) f16
  unsigned short* wqkv  = vtws  + (size_t)BT*NKV*SEQ*64;               // (1152,896) bf16
  unsigned short* wo16  = wqkv  + (size_t)1152*HID;                    // (896,896) bf16
  unsigned short* h16   = wo16  + (size_t)HID*HID;                     // (4096,896) bf16 == attn-out alias

  const int nh   = NTOK*HID;
  const int nwq  = HID*HID;
  const int nwkv = 2*64*HID;

  cvt_kernel<<<dim3(448, 5), 256, 0, stream>>>(
      hidden, Wq, Wk, Wv, Wo,
      h16, wqkv, wqkv + nwq, wqkv + nwq + nwkv, wo16,
      nh, nwq, nwkv, nwkv, nwq);

  qkv_gemm_kernel<<<dim3(NTOK/64, 9), 256, 0, stream>>>(
      h16, wqkv, bq, bk, bv, pos, qws, kws, vtws);

  attn_kernel<<<dim3(16, NH, BT), 512, 0, stream>>>(qws, kws, vtws, h16 /*aws*/);

  out_gemm_kernel<<<dim3(NTOK/64, 7), 256, 0, stream>>>(h16 /*aws*/, wo16, (float*)d_out);
}